// Round 5
// baseline (9744.241 us; speedup 1.0000x reference)
//
#include <hip/hip_runtime.h>

// ============================================================================
// fp32 I/O (R4 diagnostics: inputs/outputs are fp32; tp_w has 208896 elements).
//
// ws float-offset layout
//   [0,363)        : 11 dense w3j tables (device-computed, fp32)
//   [384, 209280)  : tp weights scaled by per-path coeff (reference layout)
//   [209280,211584): lin weights scaled by 1/sqrt(m)
//   byte 1MB...    : x-transpose [208][N] fp32
// ============================================================================
#define T000 0
#define T011 1
#define T101 10
#define T110 19
#define T022 28
#define T202 53
#define T220 78
#define T121 103
#define T211 148
#define T112 193
#define T222 238
#define NTAB 363

#define OFF_TPW 384
#define OFF_LIN (384 + 208896)
#define XT_BYTE_OFF ((size_t)1 << 20)

// tp_w per-path offsets — CORRECTED to match in_sizes[1]=208896
// (PATHS order: 000,011,022,101,110,112,121,202,211,220,222)
#define TP000 0        // 32*32*32 = 32768
#define TP011 32768    // 32*32*32 = 32768
#define TP022 65536    // 32*16*16 = 8192
#define TP101 73728    // 32*32*32 = 32768
#define TP110 106496   // 32*32*32 = 32768
#define TP112 139264   // 32*32*16 = 16384
#define TP121 155648   // 32*16*32 = 16384
#define TP202 172032   // 16*32*16 = 8192
#define TP211 180224   // 16*32*32 = 16384
#define TP220 196608   // 16*16*32 = 8192
#define TP222 204800   // 16*16*16 = 4096
#define TPEND 208896

// ============================================================================
// Device-side Wigner 3j (literal replica of reference, fp64)
// ============================================================================
struct cplx { double re, im; };
__device__ inline cplx cmul(cplx a, cplx b){ return {a.re*b.re - a.im*b.im, a.re*b.im + a.im*b.re}; }
__device__ inline cplx cconj(cplx a){ return {a.re, -a.im}; }

__device__ double dfact(int n){ double r=1; for(int i=2;i<=n;i++) r*=i; return r; }

__device__ double dcgc(int j1,int m1,int j2,int m2,int j3,int m3){
  if (m3 != m1+m2) return 0.0;
  double pref = sqrt((2.0*j3+1)*dfact(j3+j1-j2)*dfact(j3-j1+j2)*dfact(j1+j2-j3)/dfact(j1+j2+j3+1));
  pref *= sqrt(dfact(j3+m3)*dfact(j3-m3)*dfact(j1-m1)*dfact(j1+m1)*dfact(j2-m2)*dfact(j2+m2));
  int k0 = max(0, max(j2-j3-m1, j1-j3+m2));
  int k1 = min(j1+j2-j3, min(j1-m1, j2+m2));
  double s = 0.0;
  for(int k=k0;k<=k1;k++){
    double d = dfact(k)*dfact(j1+j2-j3-k)*dfact(j1-m1-k)*dfact(j2+m2-k)*dfact(j3-j2+m1+k)*dfact(j3-j1-m2+k);
    s += ((k&1)?-1.0:1.0)/d;
  }
  return pref*s;
}

__device__ void dqmat(int l, cplx* q){
  int n = 2*l+1;
  for(int i=0;i<n*n;i++) q[i] = {0.0,0.0};
  double s2 = 1.0/sqrt(2.0);
  for(int m=-l;m<0;m++){
    q[(l+m)*n + (l-m)] = {s2, 0.0};
    q[(l+m)*n + (l+m)] = {0.0, -s2};
  }
  q[l*n+l] = {1.0, 0.0};
  for(int m=1;m<=l;m++){
    double sgn = (m&1)? -1.0 : 1.0;
    q[(l+m)*n + (l+m)] = {sgn*s2, 0.0};
    q[(l+m)*n + (l-m)] = {0.0, sgn*s2};
  }
  cplx ph = {1.0,0.0}, mi = {0.0,-1.0};   // (-i)^l
  for(int t=0;t<l;t++) ph = cmul(ph, mi);
  for(int i=0;i<n*n;i++) q[i] = cmul(q[i], ph);
}

__device__ void dw3j(int l1,int l2,int l3, float* W){
  int n1=2*l1+1, n2=2*l2+1, n3=2*l3+1;
  cplx q1[25], q2[25], q3[25];
  dqmat(l1,q1); dqmat(l2,q2); dqmat(l3,q3);
  double Wd[125];
  for(int i=0;i<n1;i++)for(int j=0;j<n2;j++)for(int k=0;k<n3;k++){
    double accr = 0.0;
    for(int a=0;a<n1;a++){ int m1=a-l1;
      for(int b=0;b<n2;b++){ int m2=b-l2; int m3=m1+m2;
        if (m3 < -l3 || m3 > l3) continue;
        double C = dcgc(l1,m1,l2,m2,l3,m3);
        if (C==0.0) continue;
        int c = l3+m3;
        cplx t = cmul(q1[a*n1+i], q2[b*n2+j]);
        t = cmul(t, cconj(q3[c*n3+k]));
        accr += t.re*C;
      }
    }
    Wd[(i*n2+j)*n3+k] = accr;
  }
  double nrm = 0.0;
  for(int idx=0; idx<n1*n2*n3; idx++) nrm += Wd[idx]*Wd[idx];
  nrm = sqrt(nrm);
  for(int idx=0; idx<n1*n2*n3; idx++) W[idx] = (float)(Wd[idx]/nrm);
}

__global__ void w3j_init(float* __restrict__ ws){
  int t = threadIdx.x;
  if (t >= 11) return;
  const int spec[11][4] = {
    {0,0,0,T000},{0,1,1,T011},{1,0,1,T101},{1,1,0,T110},
    {0,2,2,T022},{2,0,2,T202},{2,2,0,T220},{1,2,1,T121},
    {2,1,1,T211},{1,1,2,T112},{2,2,2,T222}};
  dw3j(spec[t][0], spec[t][1], spec[t][2], ws + spec[t][3]);
}

// ============================================================================
// Weight scaling by path coefficient (reference layout preserved)
// ============================================================================
__global__ void prep2(const float* __restrict__ tp, const float* __restrict__ lin,
                      float* __restrict__ ws){
  const float PK0 = 1.0f/48.0f;                  // sqrt(1/2304)
  const float PK1 = 1.0f/32.0f;                  // sqrt(3/3072)
  const float PK2 = sqrtf(5.0f)/48.0f;           // sqrt(5/2304)
  int t = blockIdx.x*256 + threadIdx.x;
  if (t < TPEND){
    float c;
    if      (t < TP011) c = PK0;   // 000
    else if (t < TP022) c = PK1;   // 011
    else if (t < TP101) c = PK2;   // 022
    else if (t < TP110) c = PK1;   // 101
    else if (t < TP112) c = PK0;   // 110
    else if (t < TP121) c = PK2;   // 112
    else if (t < TP202) c = PK1;   // 121
    else if (t < TP211) c = PK2;   // 202
    else if (t < TP220) c = PK1;   // 211
    else if (t < TP222) c = PK0;   // 220
    else                c = PK2;   // 222
    ws[OFF_TPW + t] = c * tp[t];
  } else {
    int u = t - TPEND;
    if (u < 2304){
      float c = (u < 2048) ? 0.17677669529663687f /*1/sqrt(32)*/ : 0.25f;
      ws[OFF_LIN + u] = c * lin[u];
    }
  }
}

// ============================================================================
// x transpose: [N][208] -> [208][N] for coalesced per-lane (lane=node) loads
// ============================================================================
__global__ void transpose_kernel(const float* __restrict__ x, float* __restrict__ xt, int N){
  __shared__ float tile[64*209];
  int z0 = blockIdx.x*64;
  int nz = N - z0; if (nz > 64) nz = 64;
  for(int idx=threadIdx.x; idx<64*208; idx+=256){
    int zl = idx/208, d = idx - zl*208;
    float v = (zl < nz) ? x[(size_t)z0*208 + idx] : 0.f;
    tile[zl*209 + d] = v;
  }
  __syncthreads();
  for(int idx=threadIdx.x; idx<64*208; idx+=256){
    int d = idx>>6, zl = idx & 63;
    if (zl < nz) xt[(size_t)d*N + z0 + zl] = tile[zl*209 + d];
  }
}

// ============================================================================
// Main kernel: literal per-path evaluation, one thread per node
// ============================================================================
template<bool USEXT>
__global__ __launch_bounds__(256, 2)
void tp_main(const float* __restrict__ x, const float* __restrict__ xt,
             const float* __restrict__ ws, float* __restrict__ out, int N){
  __shared__ float sT[NTAB];
  for(int i=threadIdx.x; i<NTAB; i+=256) sT[i] = ws[i];
  __syncthreads();
  int z = blockIdx.x*256 + threadIdx.x;
  if (z >= N) return;
  const float* __restrict__ xz = x + (size_t)z*208;
  const size_t Ns = (size_t)N;
  auto LD = [&](int d)->float {
    if (USEXT) return xt[(size_t)d*Ns + z];
    else       return xz[d];
  };
  float* __restrict__ oz = out + (size_t)z*208;
  const float* __restrict__ W  = ws + OFF_TPW;
  const float* __restrict__ LW = ws + OFF_LIN;

  // ---------------- Phase 0: output irrep 0e ----------------
  {
    float acc[32];
#pragma unroll
    for(int w=0;w<32;w++) acc[w]=0.f;
    const float c000 = sT[T000];
    const float* wp = W + TP000;
#pragma unroll 1
    for(int u=0;u<32;u++){
      float su = c000 * LD(u);
      for(int v=0;v<32;v++){
        float p = su * LD(v);
#pragma unroll
        for(int w=0;w<32;w++) acc[w] = fmaf(p, wp[w], acc[w]);
        wp += 32;
      }
    }
    wp = W + TP110;
#pragma unroll 1
    for(int u=0;u<32;u++){
      float a0=LD(32+3*u), a1=LD(33+3*u), a2=LD(34+3*u);
      float r0 = sT[T110+0]*a0 + sT[T110+3]*a1 + sT[T110+6]*a2;
      float r1 = sT[T110+1]*a0 + sT[T110+4]*a1 + sT[T110+7]*a2;
      float r2 = sT[T110+2]*a0 + sT[T110+5]*a1 + sT[T110+8]*a2;
      for(int v=0;v<32;v++){
        float p = r0*LD(32+3*v) + r1*LD(33+3*v) + r2*LD(34+3*v);
#pragma unroll
        for(int w=0;w<32;w++) acc[w] = fmaf(p, wp[w], acc[w]);
        wp += 32;
      }
    }
    wp = W + TP220;
#pragma unroll 1
    for(int u=0;u<16;u++){
      float a[5], r[5];
#pragma unroll
      for(int j=0;j<5;j++) a[j]=LD(128+5*u+j);
#pragma unroll
      for(int j=0;j<5;j++){
        float s=0.f;
#pragma unroll
        for(int i=0;i<5;i++) s = fmaf(sT[T220+i*5+j], a[i], s);
        r[j]=s;
      }
      for(int v=0;v<16;v++){
        float p = r[0]*LD(128+5*v)+r[1]*LD(129+5*v)+r[2]*LD(130+5*v)+r[3]*LD(131+5*v)+r[4]*LD(132+5*v);
#pragma unroll
        for(int w=0;w<32;w++) acc[w]=fmaf(p,wp[w],acc[w]);
        wp += 32;
      }
    }
    const float* lw = LW + 0;
#pragma unroll 1
    for(int u=0;u<32;u++){
      float su = LD(u);
#pragma unroll
      for(int w=0;w<32;w++) acc[w]=fmaf(su,lw[w],acc[w]);
      lw += 32;
    }
#pragma unroll
    for(int w=0;w<32;w++) oz[w]=acc[w];
  }

  // ---------------- Phase 1: output irrep 1o ----------------
  {
    float acc[96];
#pragma unroll
    for(int i=0;i<96;i++) acc[i]=0.f;
    const float* wp = W + TP011;
#pragma unroll 1
    for(int u=0;u<32;u++){
      float su = LD(u);
      for(int v=0;v<32;v++){
        float v0=LD(32+3*v), v1=LD(33+3*v), v2=LD(34+3*v);
        float p0 = su*(sT[T011+0]*v0 + sT[T011+3]*v1 + sT[T011+6]*v2);
        float p1 = su*(sT[T011+1]*v0 + sT[T011+4]*v1 + sT[T011+7]*v2);
        float p2 = su*(sT[T011+2]*v0 + sT[T011+5]*v1 + sT[T011+8]*v2);
#pragma unroll
        for(int w=0;w<32;w++){
          float wt = wp[w];
          acc[3*w  ] = fmaf(p0, wt, acc[3*w  ]);
          acc[3*w+1] = fmaf(p1, wt, acc[3*w+1]);
          acc[3*w+2] = fmaf(p2, wt, acc[3*w+2]);
        }
        wp += 32;
      }
    }
    wp = W + TP101;
#pragma unroll 1
    for(int u=0;u<32;u++){
      float u0=LD(32+3*u), u1=LD(33+3*u), u2=LD(34+3*u);
      float q0 = sT[T101+0]*u0 + sT[T101+3]*u1 + sT[T101+6]*u2;
      float q1 = sT[T101+1]*u0 + sT[T101+4]*u1 + sT[T101+7]*u2;
      float q2 = sT[T101+2]*u0 + sT[T101+5]*u1 + sT[T101+8]*u2;
      for(int v=0;v<32;v++){
        float sv = LD(v);
        float p0=sv*q0, p1=sv*q1, p2=sv*q2;
#pragma unroll
        for(int w=0;w<32;w++){
          float wt = wp[w];
          acc[3*w  ] = fmaf(p0, wt, acc[3*w  ]);
          acc[3*w+1] = fmaf(p1, wt, acc[3*w+1]);
          acc[3*w+2] = fmaf(p2, wt, acc[3*w+2]);
        }
        wp += 32;
      }
    }
    // 121: weights [u:32][tc:16][w:32]
#pragma unroll 1
    for(int tc=0; tc<16; tc++){
      float tv[5];
#pragma unroll
      for(int j=0;j<5;j++) tv[j]=LD(128+5*tc+j);
      float q[9];
#pragma unroll
      for(int i=0;i<3;i++)
#pragma unroll
        for(int c=0;c<3;c++){
          float s=0.f;
#pragma unroll
          for(int j=0;j<5;j++) s = fmaf(sT[T121+(i*5+j)*3+c], tv[j], s);
          q[i*3+c]=s;
        }
      for(int u=0;u<32;u++){
        float u0=LD(32+3*u), u1=LD(33+3*u), u2=LD(34+3*u);
        float p0 = u0*q[0] + u1*q[3] + u2*q[6];
        float p1 = u0*q[1] + u1*q[4] + u2*q[7];
        float p2 = u0*q[2] + u1*q[5] + u2*q[8];
        const float* wq = W + TP121 + (u*16+tc)*32;
#pragma unroll
        for(int w=0;w<32;w++){
          float wt = wq[w];
          acc[3*w  ] = fmaf(p0, wt, acc[3*w  ]);
          acc[3*w+1] = fmaf(p1, wt, acc[3*w+1]);
          acc[3*w+2] = fmaf(p2, wt, acc[3*w+2]);
        }
      }
    }
    wp = W + TP211;
#pragma unroll 1
    for(int u=0;u<16;u++){
      float tu[5];
#pragma unroll
      for(int j=0;j<5;j++) tu[j]=LD(128+5*u+j);
      float r[9];
#pragma unroll
      for(int b=0;b<3;b++)
#pragma unroll
        for(int c=0;c<3;c++){
          float s=0.f;
#pragma unroll
          for(int a=0;a<5;a++) s = fmaf(sT[T211+(a*3+b)*3+c], tu[a], s);
          r[b*3+c]=s;
        }
      for(int v=0;v<32;v++){
        float v0=LD(32+3*v), v1=LD(33+3*v), v2=LD(34+3*v);
        float p0 = v0*r[0] + v1*r[3] + v2*r[6];
        float p1 = v0*r[1] + v1*r[4] + v2*r[7];
        float p2 = v0*r[2] + v1*r[5] + v2*r[8];
#pragma unroll
        for(int w=0;w<32;w++){
          float wt = wp[w];
          acc[3*w  ] = fmaf(p0, wt, acc[3*w  ]);
          acc[3*w+1] = fmaf(p1, wt, acc[3*w+1]);
          acc[3*w+2] = fmaf(p2, wt, acc[3*w+2]);
        }
        wp += 32;
      }
    }
    const float* lw = LW + 1024;
#pragma unroll 1
    for(int u=0;u<32;u++){
      float u0=LD(32+3*u), u1=LD(33+3*u), u2=LD(34+3*u);
#pragma unroll
      for(int w=0;w<32;w++){
        float wt = lw[w];
        acc[3*w  ] = fmaf(u0, wt, acc[3*w  ]);
        acc[3*w+1] = fmaf(u1, wt, acc[3*w+1]);
        acc[3*w+2] = fmaf(u2, wt, acc[3*w+2]);
      }
      lw += 32;
    }
#pragma unroll
    for(int i=0;i<96;i++) oz[32+i]=acc[i];
  }

  // ---------------- Phase 2: output irrep 2e ----------------
  {
    float acc[80];
#pragma unroll
    for(int i=0;i<80;i++) acc[i]=0.f;
    const float* wp = W + TP022;
#pragma unroll 1
    for(int u=0;u<32;u++){
      float su = LD(u);
      for(int v=0;v<16;v++){
        float tv[5], p[5];
#pragma unroll
        for(int j=0;j<5;j++) tv[j]=LD(128+5*v+j);
#pragma unroll
        for(int c=0;c<5;c++){
          float s=0.f;
#pragma unroll
          for(int j=0;j<5;j++) s = fmaf(sT[T022+j*5+c], tv[j], s);
          p[c] = su*s;
        }
#pragma unroll
        for(int w=0;w<16;w++){
          float wt=wp[w];
#pragma unroll
          for(int c=0;c<5;c++) acc[5*w+c] = fmaf(p[c], wt, acc[5*w+c]);
        }
        wp += 16;
      }
    }
    wp = W + TP112;
#pragma unroll 1
    for(int u=0;u<32;u++){
      float u0=LD(32+3*u), u1=LD(33+3*u), u2=LD(34+3*u);
      float r[15];
#pragma unroll
      for(int j=0;j<3;j++)
#pragma unroll
        for(int c=0;c<5;c++)
          r[j*5+c] = sT[T112+(0*3+j)*5+c]*u0 + sT[T112+(1*3+j)*5+c]*u1 + sT[T112+(2*3+j)*5+c]*u2;
      for(int v=0;v<32;v++){
        float v0=LD(32+3*v), v1=LD(33+3*v), v2=LD(34+3*v);
        float p[5];
#pragma unroll
        for(int c=0;c<5;c++) p[c] = v0*r[c] + v1*r[5+c] + v2*r[10+c];
#pragma unroll
        for(int w=0;w<16;w++){
          float wt=wp[w];
#pragma unroll
          for(int c=0;c<5;c++) acc[5*w+c] = fmaf(p[c], wt, acc[5*w+c]);
        }
        wp += 16;
      }
    }
    wp = W + TP202;
#pragma unroll 1
    for(int u=0;u<16;u++){
      float tu[5], q[5];
#pragma unroll
      for(int j=0;j<5;j++) tu[j]=LD(128+5*u+j);
#pragma unroll
      for(int c=0;c<5;c++){
        float s=0.f;
#pragma unroll
        for(int i=0;i<5;i++) s = fmaf(sT[T202+i*5+c], tu[i], s);
        q[c]=s;
      }
      for(int v=0;v<32;v++){
        float sv = LD(v);
        float p[5];
#pragma unroll
        for(int c=0;c<5;c++) p[c]=sv*q[c];
#pragma unroll
        for(int w=0;w<16;w++){
          float wt=wp[w];
#pragma unroll
          for(int c=0;c<5;c++) acc[5*w+c]=fmaf(p[c],wt,acc[5*w+c]);
        }
        wp += 16;
      }
    }
    wp = W + TP222;
#pragma unroll 1
    for(int u=0;u<16;u++){
      float tu[5];
#pragma unroll
      for(int j=0;j<5;j++) tu[j]=LD(128+5*u+j);
      float r[25];
#pragma unroll
      for(int j=0;j<5;j++)
#pragma unroll
        for(int c=0;c<5;c++){
          float s=0.f;
#pragma unroll
          for(int i=0;i<5;i++) s = fmaf(sT[T222+(i*5+j)*5+c], tu[i], s);
          r[j*5+c]=s;
        }
      for(int v=0;v<16;v++){
        float s0=LD(128+5*v),s1=LD(129+5*v),s2=LD(130+5*v),s3=LD(131+5*v),s4=LD(132+5*v);
        float p[5];
#pragma unroll
        for(int c=0;c<5;c++) p[c] = s0*r[c]+s1*r[5+c]+s2*r[10+c]+s3*r[15+c]+s4*r[20+c];
#pragma unroll
        for(int w=0;w<16;w++){
          float wt=wp[w];
#pragma unroll
          for(int c=0;c<5;c++) acc[5*w+c]=fmaf(p[c],wt,acc[5*w+c]);
        }
        wp += 16;
      }
    }
    const float* lw = LW + 2048;
#pragma unroll 1
    for(int u=0;u<16;u++){
      float t0=LD(128+5*u),t1=LD(129+5*u),t2=LD(130+5*u),t3=LD(131+5*u),t4=LD(132+5*u);
#pragma unroll
      for(int w=0;w<16;w++){
        float wt=lw[w];
        acc[5*w  ] = fmaf(t0, wt, acc[5*w  ]);
        acc[5*w+1] = fmaf(t1, wt, acc[5*w+1]);
        acc[5*w+2] = fmaf(t2, wt, acc[5*w+2]);
        acc[5*w+3] = fmaf(t3, wt, acc[5*w+3]);
        acc[5*w+4] = fmaf(t4, wt, acc[5*w+4]);
      }
      lw += 16;
    }
#pragma unroll
    for(int i=0;i<80;i++) oz[128+i]=acc[i];
  }
}

// ============================================================================
extern "C" void kernel_launch(void* const* d_in, const int* in_sizes, int n_in,
                              void* d_out, int out_size, void* d_ws, size_t ws_size,
                              hipStream_t stream) {
  const float* x   = (const float*)d_in[0];
  const float* tpw = (const float*)d_in[1];
  const float* lnw = (const float*)d_in[2];
  float* out = (float*)d_out;
  float* ws  = (float*)d_ws;
  const int N = in_sizes[0]/208;

  w3j_init<<<1, 64, 0, stream>>>(ws);
  const int prep_threads = TPEND + 2304;
  prep2<<<(prep_threads+255)/256, 256, 0, stream>>>(tpw, lnw, ws);

  const size_t xt_need = XT_BYTE_OFF + (size_t)N*208*sizeof(float);
  float* xt = (float*)((char*)d_ws + XT_BYTE_OFF);
  if (ws_size >= xt_need) {
    transpose_kernel<<<(N+63)/64, 256, 0, stream>>>(x, xt, N);
    tp_main<true><<<(N+255)/256, 256, 0, stream>>>(x, xt, ws, out, N);
  } else {
    tp_main<false><<<(N+255)/256, 256, 0, stream>>>(x, xt, ws, out, N);
  }
}

// Round 6
// 2770.187 us; speedup vs baseline: 3.5175x; 3.5175x over previous
//
#include <hip/hip_runtime.h>

// ============================================================================
// fp32 I/O. Passing R5 baseline restructured:
//  - parallel device-side w3j construction (was 3.4ms serial)
//  - exact path symmetrization (u<=v) + transpose-merging (011+101, 022+202,
//    121+211): 456k -> 313k FMA/thread, weight stream 846KB -> 424KB
//  - 3 phases fused in one dispatch, launch_bounds(256,4) for occupancy
//
// ws float layout:
//   [0,363)    w3j tables
//   [512,...)  merged/symmetrized weights (see OFF_*)
//   byte 1MB.. x-transpose [208][N]
// ============================================================================
#define T000 0
#define T011 1
#define T101 10
#define T110 19
#define T022 28
#define T202 53
#define T220 78
#define T121 103
#define T211 148
#define T112 193
#define T222 238
#define NTAB 363

// source tp_w offsets (verified: total 208896)
#define TP000 0
#define TP011 32768
#define TP022 65536
#define TP101 73728
#define TP110 106496
#define TP112 139264
#define TP121 155648
#define TP202 172032
#define TP211 180224
#define TP220 196608
#define TP222 204800
#define TPEND 208896

// destination (prepared) weight offsets
#define OFF_CW000 512      // [pid528][w32]
#define OFF_CW110 17408    // [pid528][w32]
#define OFF_CW220 34304    // [pid136][w32]
#define OFF_CW011 38656    // [q32][p32][w32]  merged 011+101
#define OFF_CW121 71424    // [b16][q32][w32]  merged 121+211
#define OFF_CW022 87808    // [b16][p32][w16]  merged 022+202
#define OFF_CW112 96000    // [pid528][w16]
#define OFF_CW222 104448   // [pid136][w16]
#define OFF_LIN0  106624   // [32][32]
#define OFF_LIN1  107648   // [32][32]
#define OFF_LIN2  108672   // [16][16]
#define PREP_THREADS 108416
#define XT_BYTE_OFF ((size_t)1 << 20)

// ============================================================================
// Parallel device-side Wigner 3j (literal reference math, fp64, 1 thr/element)
// ============================================================================
struct cplx { double re, im; };
__device__ inline cplx cmul(cplx a, cplx b){ return {a.re*b.re - a.im*b.im, a.re*b.im + a.im*b.re}; }

__device__ double dfact(int n){ double r=1; for(int i=2;i<=n;i++) r*=i; return r; }

__device__ double dcgc(int j1,int m1,int j2,int m2,int j3,int m3){
  if (m3 != m1+m2) return 0.0;
  double pref = sqrt((2.0*j3+1)*dfact(j3+j1-j2)*dfact(j3-j1+j2)*dfact(j1+j2-j3)/dfact(j1+j2+j3+1));
  pref *= sqrt(dfact(j3+m3)*dfact(j3-m3)*dfact(j1-m1)*dfact(j1+m1)*dfact(j2-m2)*dfact(j2+m2));
  int k0 = max(0, max(j2-j3-m1, j1-j3+m2));
  int k1 = min(j1+j2-j3, min(j1-m1, j2+m2));
  double s = 0.0;
  for(int k=k0;k<=k1;k++){
    double d = dfact(k)*dfact(j1+j2-j3-k)*dfact(j1-m1-k)*dfact(j2+m2-k)*dfact(j3-j2+m1+k)*dfact(j3-j1-m2+k);
    s += ((k&1)?-1.0:1.0)/d;
  }
  return pref*s;
}

// element (row a, col c) of the real<->complex change-of-basis q(l), incl (-i)^l
__device__ cplx qel(int l, int a, int c){
  const double s2 = 0.7071067811865475244;
  cplx base = {0.0, 0.0};
  if (a < l){                      // m = a-l < 0
    if (c == 2*l-a) base = {s2, 0.0};
    else if (c == a) base = {0.0, -s2};
  } else if (a == l){
    if (c == l) base = {1.0, 0.0};
  } else {                         // m = a-l > 0
    double sgn = ((a-l)&1)? -1.0 : 1.0;
    if (c == a) base = {sgn*s2, 0.0};
    else if (c == 2*l-a) base = {0.0, sgn*s2};
  }
  cplx ph = {1.0,0.0}, mi = {0.0,-1.0};
  for(int t=0;t<l;t++) ph = cmul(ph, mi);
  return cmul(base, ph);
}

__global__ void w3j_init(float* __restrict__ ws){
  __shared__ double red[128];
  __shared__ double snorm;
  const int spec[11][4] = {
    {0,0,0,T000},{0,1,1,T011},{1,0,1,T101},{1,1,0,T110},
    {0,2,2,T022},{2,0,2,T202},{2,2,0,T220},{1,2,1,T121},
    {2,1,1,T211},{1,1,2,T112},{2,2,2,T222}};
  int tbl = blockIdx.x;
  int l1 = spec[tbl][0], l2 = spec[tbl][1], l3 = spec[tbl][2], off = spec[tbl][3];
  int n1 = 2*l1+1, n2 = 2*l2+1, n3 = 2*l3+1, nel = n1*n2*n3;
  int t = threadIdx.x;
  double val = 0.0;
  if (t < nel){
    int k = t % n3, j = (t/n3) % n2, i = t/(n3*n2);
    for(int a=0;a<n1;a++){ int m1 = a-l1;
      for(int b=0;b<n2;b++){ int m2 = b-l2, m3 = m1+m2;
        if (m3 < -l3 || m3 > l3) continue;
        double C = dcgc(l1,m1,l2,m2,l3,m3);
        if (C == 0.0) continue;
        cplx q1 = qel(l1,a,i), q2 = qel(l2,b,j), q3 = qel(l3,l3+m3,k);
        q3.im = -q3.im;                       // conj
        cplx p = cmul(cmul(q1,q2), q3);
        val += p.re * C;
      }
    }
  }
  red[t] = val*val;
  __syncthreads();
  for(int s=64; s>0; s>>=1){
    if (t < s) red[t] += red[t+s];
    __syncthreads();
  }
  if (t == 0) snorm = sqrt(red[0]);
  __syncthreads();
  if (t < nel) ws[off + t] = (float)(val / snorm);
}

// ============================================================================
// Weight prep: symmetrize (u<=v) + transpose-merge + fold coeffs
// ============================================================================
__device__ inline void pdec(int pid, int m, int& u, int& v){
  int uu = 0;
  while (pid >= m-uu){ pid -= (m-uu); uu++; }
  u = uu; v = uu + pid;
}

__global__ void prep3(const float* __restrict__ tp, const float* __restrict__ lin,
                      float* __restrict__ ws){
  const float PK0 = 1.0f/48.0f;
  const float PK1 = 1.0f/32.0f;
  const float PK2 = sqrtf(5.0f)/48.0f;
  int t = blockIdx.x*256 + threadIdx.x;
  if (t >= PREP_THREADS) return;
  if (t < 16896){                               // cw000p
    int w = t & 31, pid = t >> 5; int u,v; pdec(pid,32,u,v);
    float s = tp[TP000+(u*32+v)*32+w];
    if (u < v) s += tp[TP000+(v*32+u)*32+w];
    ws[OFF_CW000 + t] = PK0 * ws[T000] * s; return;
  }
  t -= 16896;
  if (t < 16896){                               // cw110p (d110 folded)
    int w = t & 31, pid = t >> 5; int u,v; pdec(pid,32,u,v);
    float s = tp[TP110+(u*32+v)*32+w];
    if (u < v) s += tp[TP110+(v*32+u)*32+w];
    ws[OFF_CW110 + 16896 + t - 16896] = PK0 * ws[T110] * s;  // == OFF_CW110+t
    return;
  }
  t -= 16896;
  if (t < 4352){                                // cw220p (d220 folded)
    int w = t & 31, pid = t >> 5; int u,v; pdec(pid,16,u,v);
    float s = tp[TP220+(u*16+v)*32+w];
    if (u < v) s += tp[TP220+(v*16+u)*32+w];
    ws[OFF_CW220 + t] = PK0 * ws[T220] * s; return;
  }
  t -= 4352;
  if (t < 32768){                               // cw011m [q][p][w]
    int w = t & 31, r = t >> 5; int p = r & 31, q = r >> 5;
    float d011 = ws[T011], d101 = ws[T101];
    float s = d011 * tp[TP011+(p*32+q)*32+w] + d101 * tp[TP101+(q*32+p)*32+w];
    ws[OFF_CW011 + t] = PK1 * s; return;
  }
  t -= 32768;
  if (t < 16384){                               // cw121m [b][q][w]
    int w = t & 31, r = t >> 5; int q = r & 31, b = r >> 5;
    float s = tp[TP121+(q*16+b)*32+w] + tp[TP211+(b*32+q)*32+w];
    ws[OFF_CW121 + t] = PK1 * s; return;
  }
  t -= 16384;
  if (t < 8192){                                // cw022m [b][p][w16]
    int w = t & 15, r = t >> 4; int p = r & 31, b = r >> 5;
    float d022 = ws[T022], d202 = ws[T202];
    float s = d022 * tp[TP022+(p*16+b)*16+w] + d202 * tp[TP202+(b*32+p)*16+w];
    ws[OFF_CW022 + t] = PK2 * s; return;
  }
  t -= 8192;
  if (t < 8448){                                // cw112p
    int w = t & 15, pid = t >> 4; int u,v; pdec(pid,32,u,v);
    float s = tp[TP112+(u*32+v)*16+w];
    if (u < v) s += tp[TP112+(v*32+u)*16+w];
    ws[OFF_CW112 + t] = PK2 * s; return;
  }
  t -= 8448;
  if (t < 2176){                                // cw222p
    int w = t & 15, pid = t >> 4; int u,v; pdec(pid,16,u,v);
    float s = tp[TP222+(u*16+v)*16+w];
    if (u < v) s += tp[TP222+(v*16+u)*16+w];
    ws[OFF_CW222 + t] = PK2 * s; return;
  }
  t -= 2176;
  if (t < 1024){ ws[OFF_LIN0 + t] = 0.17677669529663687f * lin[t]; return; }
  t -= 1024;
  if (t < 1024){ ws[OFF_LIN1 + t] = 0.17677669529663687f * lin[1024+t]; return; }
  t -= 1024;
  ws[OFF_LIN2 + t] = 0.25f * lin[2048+t];
}

// ============================================================================
// x transpose: [N][208] -> [208][N]
// ============================================================================
__global__ void transpose_kernel(const float* __restrict__ x, float* __restrict__ xt, int N){
  __shared__ float tile[64*209];
  int z0 = blockIdx.x*64;
  int nz = N - z0; if (nz > 64) nz = 64;
  for(int idx=threadIdx.x; idx<64*208; idx+=256){
    int zl = idx/208, d = idx - zl*208;
    float v = (zl < nz) ? x[(size_t)z0*208 + idx] : 0.f;
    tile[zl*209 + d] = v;
  }
  __syncthreads();
  for(int idx=threadIdx.x; idx<64*208; idx+=256){
    int d = idx>>6, zl = idx & 63;
    if (zl < nz) xt[(size_t)d*N + z0 + zl] = tile[zl*209 + d];
  }
}

// ============================================================================
// Fused 3-phase main kernel: phase = blockIdx.x / NB
// ============================================================================
__global__ __launch_bounds__(256, 4)
void tp_fused(const float* __restrict__ xt, const float* __restrict__ ws,
              float* __restrict__ out, int N, int NB){
  __shared__ float sT[NTAB];
  for(int i=threadIdx.x; i<NTAB; i+=256) sT[i] = ws[i];
  __syncthreads();
  int phase = blockIdx.x / NB;
  int z = (blockIdx.x % NB)*256 + threadIdx.x;
  if (z >= N) return;
  const size_t Ns = (size_t)N;
#define XT(d) xt[(size_t)(d)*Ns + z]
  float* __restrict__ oz = out + (size_t)z*208;

  if (phase == 0){
    // ---------------- out irrep 0e (32) ----------------
    float acc[32];
#pragma unroll
    for(int w=0;w<32;w++) acc[w]=0.f;
    const float* wp = ws + OFF_CW000;
#pragma unroll 1
    for(int u=0;u<32;u++){
      float su = XT(u);
#pragma unroll 1
      for(int v=u;v<32;v++){
        float p = su * XT(v);
#pragma unroll
        for(int w=0;w<32;w++) acc[w] = fmaf(p, wp[w], acc[w]);
        wp += 32;
      }
    }
    const float* lw = ws + OFF_LIN0;
#pragma unroll 1
    for(int u=0;u<32;u++){
      float su = XT(u);
#pragma unroll
      for(int w=0;w<32;w++) acc[w] = fmaf(su, lw[w], acc[w]);
      lw += 32;
    }
    wp = ws + OFF_CW110;
#pragma unroll 1
    for(int u=0;u<32;u++){
      float a0=XT(32+3*u), a1=XT(33+3*u), a2=XT(34+3*u);
#pragma unroll 1
      for(int v=u;v<32;v++){
        float p = a0*XT(32+3*v) + a1*XT(33+3*v) + a2*XT(34+3*v);
#pragma unroll
        for(int w=0;w<32;w++) acc[w] = fmaf(p, wp[w], acc[w]);
        wp += 32;
      }
    }
    wp = ws + OFF_CW220;
#pragma unroll 1
    for(int u=0;u<16;u++){
      float b0=XT(128+5*u),b1=XT(129+5*u),b2=XT(130+5*u),b3=XT(131+5*u),b4=XT(132+5*u);
#pragma unroll 1
      for(int v=u;v<16;v++){
        float p = b0*XT(128+5*v)+b1*XT(129+5*v)+b2*XT(130+5*v)+b3*XT(131+5*v)+b4*XT(132+5*v);
#pragma unroll
        for(int w=0;w<32;w++) acc[w] = fmaf(p, wp[w], acc[w]);
        wp += 32;
      }
    }
#pragma unroll
    for(int w=0;w<32;w++) oz[w] = acc[w];

  } else if (phase == 1){
    // ---------------- out irrep 1o (32 x 3) ----------------
    float acc[96];
#pragma unroll
    for(int i=0;i<96;i++) acc[i]=0.f;
    const float* wp = ws + OFF_CW011;         // [q][p][w]
#pragma unroll 1
    for(int q=0;q<32;q++){
      float vq0=XT(32+3*q), vq1=XT(33+3*q), vq2=XT(34+3*q);
#pragma unroll 1
      for(int p=0;p<32;p++){
        float sp = XT(p);
        float p0=sp*vq0, p1=sp*vq1, p2=sp*vq2;
#pragma unroll
        for(int w=0;w<32;w++){
          float wt = wp[w];
          acc[3*w  ] = fmaf(p0, wt, acc[3*w  ]);
          acc[3*w+1] = fmaf(p1, wt, acc[3*w+1]);
          acc[3*w+2] = fmaf(p2, wt, acc[3*w+2]);
        }
        wp += 32;
      }
    }
    wp = ws + OFF_CW121;                      // [b][q][w]
#pragma unroll 1
    for(int b=0;b<16;b++){
      float t0=XT(128+5*b),t1=XT(129+5*b),t2=XT(130+5*b),t3=XT(131+5*b),t4=XT(132+5*b);
      float q9[9];
#pragma unroll
      for(int a=0;a<3;a++)
#pragma unroll
        for(int c=0;c<3;c++){
          float s = sT[T121+(a*5+0)*3+c]*t0 + sT[T121+(a*5+1)*3+c]*t1
                  + sT[T121+(a*5+2)*3+c]*t2 + sT[T121+(a*5+3)*3+c]*t3
                  + sT[T121+(a*5+4)*3+c]*t4;
          q9[a*3+c] = s;
        }
#pragma unroll 1
      for(int q=0;q<32;q++){
        float v0=XT(32+3*q), v1=XT(33+3*q), v2=XT(34+3*q);
        float p0 = v0*q9[0] + v1*q9[3] + v2*q9[6];
        float p1 = v0*q9[1] + v1*q9[4] + v2*q9[7];
        float p2 = v0*q9[2] + v1*q9[5] + v2*q9[8];
#pragma unroll
        for(int w=0;w<32;w++){
          float wt = wp[w];
          acc[3*w  ] = fmaf(p0, wt, acc[3*w  ]);
          acc[3*w+1] = fmaf(p1, wt, acc[3*w+1]);
          acc[3*w+2] = fmaf(p2, wt, acc[3*w+2]);
        }
        wp += 32;
      }
    }
    const float* lw = ws + OFF_LIN1;
#pragma unroll 1
    for(int u=0;u<32;u++){
      float v0=XT(32+3*u), v1=XT(33+3*u), v2=XT(34+3*u);
#pragma unroll
      for(int w=0;w<32;w++){
        float wt = lw[w];
        acc[3*w  ] = fmaf(v0, wt, acc[3*w  ]);
        acc[3*w+1] = fmaf(v1, wt, acc[3*w+1]);
        acc[3*w+2] = fmaf(v2, wt, acc[3*w+2]);
      }
      lw += 32;
    }
#pragma unroll
    for(int i=0;i<96;i++) oz[32+i] = acc[i];

  } else {
    // ---------------- out irrep 2e (16 x 5) ----------------
    float acc[80];
#pragma unroll
    for(int i=0;i<80;i++) acc[i]=0.f;
    const float* wp = ws + OFF_CW022;         // [b][p][w16]
#pragma unroll 1
    for(int b=0;b<16;b++){
      float t0=XT(128+5*b),t1=XT(129+5*b),t2=XT(130+5*b),t3=XT(131+5*b),t4=XT(132+5*b);
#pragma unroll 1
      for(int p=0;p<32;p++){
        float sp = XT(p);
        float p0=sp*t0,p1=sp*t1,p2=sp*t2,p3=sp*t3,p4=sp*t4;
#pragma unroll
        for(int w=0;w<16;w++){
          float wt = wp[w];
          acc[5*w  ] = fmaf(p0, wt, acc[5*w  ]);
          acc[5*w+1] = fmaf(p1, wt, acc[5*w+1]);
          acc[5*w+2] = fmaf(p2, wt, acc[5*w+2]);
          acc[5*w+3] = fmaf(p3, wt, acc[5*w+3]);
          acc[5*w+4] = fmaf(p4, wt, acc[5*w+4]);
        }
        wp += 16;
      }
    }
    wp = ws + OFF_CW222;                      // [pid136][w16]
#pragma unroll 1
    for(int u=0;u<16;u++){
      float tu[5];
#pragma unroll
      for(int j=0;j<5;j++) tu[j]=XT(128+5*u+j);
      float r[25];
#pragma unroll
      for(int b=0;b<5;b++)
#pragma unroll
        for(int c=0;c<5;c++){
          float s=0.f;
#pragma unroll
          for(int a=0;a<5;a++) s = fmaf(sT[T222+(a*5+b)*5+c], tu[a], s);
          r[b*5+c]=s;
        }
#pragma unroll 1
      for(int v=u;v<16;v++){
        float s0=XT(128+5*v),s1=XT(129+5*v),s2=XT(130+5*v),s3=XT(131+5*v),s4=XT(132+5*v);
        float p[5];
#pragma unroll
        for(int c=0;c<5;c++) p[c] = s0*r[c]+s1*r[5+c]+s2*r[10+c]+s3*r[15+c]+s4*r[20+c];
#pragma unroll
        for(int w=0;w<16;w++){
          float wt = wp[w];
#pragma unroll
          for(int c=0;c<5;c++) acc[5*w+c] = fmaf(p[c], wt, acc[5*w+c]);
        }
        wp += 16;
      }
    }
    const float* lw = ws + OFF_LIN2;
#pragma unroll 1
    for(int u=0;u<16;u++){
      float t0=XT(128+5*u),t1=XT(129+5*u),t2=XT(130+5*u),t3=XT(131+5*u),t4=XT(132+5*u);
#pragma unroll
      for(int w=0;w<16;w++){
        float wt = lw[w];
        acc[5*w  ] = fmaf(t0, wt, acc[5*w  ]);
        acc[5*w+1] = fmaf(t1, wt, acc[5*w+1]);
        acc[5*w+2] = fmaf(t2, wt, acc[5*w+2]);
        acc[5*w+3] = fmaf(t3, wt, acc[5*w+3]);
        acc[5*w+4] = fmaf(t4, wt, acc[5*w+4]);
      }
      lw += 16;
    }
    wp = ws + OFF_CW112;                      // [pid528][w16]
#pragma unroll 1
    for(int u=0;u<32;u++){
      float u0=XT(32+3*u), u1=XT(33+3*u), u2=XT(34+3*u);
      float r[15];
#pragma unroll
      for(int b=0;b<3;b++)
#pragma unroll
        for(int c=0;c<5;c++)
          r[b*5+c] = sT[T112+(0*3+b)*5+c]*u0 + sT[T112+(1*3+b)*5+c]*u1
                   + sT[T112+(2*3+b)*5+c]*u2;
#pragma unroll 1
      for(int v=u;v<32;v++){
        float v0=XT(32+3*v), v1=XT(33+3*v), v2=XT(34+3*v);
        float p[5];
#pragma unroll
        for(int c=0;c<5;c++) p[c] = v0*r[c] + v1*r[5+c] + v2*r[10+c];
#pragma unroll
        for(int w=0;w<16;w++){
          float wt = wp[w];
#pragma unroll
          for(int c=0;c<5;c++) acc[5*w+c] = fmaf(p[c], wt, acc[5*w+c]);
        }
        wp += 16;
      }
    }
#pragma unroll
    for(int i=0;i<80;i++) oz[128+i] = acc[i];
  }
#undef XT
}

// ============================================================================
extern "C" void kernel_launch(void* const* d_in, const int* in_sizes, int n_in,
                              void* d_out, int out_size, void* d_ws, size_t ws_size,
                              hipStream_t stream) {
  const float* x   = (const float*)d_in[0];
  const float* tpw = (const float*)d_in[1];
  const float* lnw = (const float*)d_in[2];
  float* out = (float*)d_out;
  float* ws  = (float*)d_ws;
  const int N = in_sizes[0]/208;
  const int NB = (N + 255)/256;

  w3j_init<<<11, 128, 0, stream>>>(ws);
  prep3<<<(PREP_THREADS+255)/256, 256, 0, stream>>>(tpw, lnw, ws);

  float* xt = (float*)((char*)d_ws + XT_BYTE_OFF);
  transpose_kernel<<<(N+63)/64, 256, 0, stream>>>(x, xt, N);
  tp_fused<<<3*NB, 256, 0, stream>>>(xt, ws, out, N, NB);
}